// Round 3
// baseline (877.629 us; speedup 1.0000x reference)
//
#include <hip/hip_runtime.h>
#include <hip/hip_bf16.h>

typedef float f32x4 __attribute__((ext_vector_type(4)));
typedef short short8 __attribute__((ext_vector_type(8)));
typedef unsigned short u16x4 __attribute__((ext_vector_type(4)));
typedef int int4v __attribute__((ext_vector_type(4)));

#define N_B 16
#define L_DIM 2048
#define S_DIM 2048
#define D_DIM 128
#define CSTRIDE 80   // chunk LDS leading dim (16-short pad: breaks bank alignment)

static __device__ __forceinline__ unsigned short f2bf(float f) {
  unsigned int u = __builtin_bit_cast(unsigned int, f);
  u = u + 0x7fffu + ((u >> 16) & 1u);
  return (unsigned short)(u >> 16);
}

// ---------- pre-kernel 0: detect mask element width ----------
__global__ void detect_mask_kernel(const unsigned int* __restrict__ m, int* __restrict__ flag) {
  __shared__ unsigned int red[256];
  unsigned int v = 0;
  for (int i = threadIdx.x; i < 16384; i += 256) v |= m[i];
  red[threadIdx.x] = v;
  __syncthreads();
  if (threadIdx.x == 0) {
    unsigned int o = 0;
#pragma unroll
    for (int i = 0; i < 256; ++i) o |= red[i];
    *flag = (o > 1u) ? 1 : 0;
  }
}

// ---------- pre-kernel 1: pack mask to bits (1 bit per (l,s) position) ----------
// bit=1 -> masked. Wave-coalesced: 64 lanes read 64 consecutive elems, ballot, 1 u64 store.
__global__ void pack_mask_kernel(const void* __restrict__ mraw, const int* __restrict__ flagp,
                                 unsigned long long* __restrict__ bits) {
  const int byte_mode = *flagp;
  const size_t total = (size_t)N_B * L_DIM * S_DIM;
  const size_t stride = (size_t)gridDim.x * blockDim.x;
  for (size_t i = (size_t)blockIdx.x * blockDim.x + threadIdx.x; i < total; i += stride) {
    int v;
    if (byte_mode) v = ((const unsigned char*)mraw)[i] != 0;
    else           v = ((const int*)mraw)[i] != 0;
    unsigned long long b = __ballot(v);
    if ((threadIdx.x & 63) == 0) bits[i >> 6] = b;
  }
}

// ---------- pre-kernel 2: K fp32 -> bf16 ----------
__global__ void cvt_k_kernel(const float* __restrict__ K, unsigned short* __restrict__ Kb) {
  const int total4 = N_B * S_DIM * D_DIM / 4;
  for (int i = blockIdx.x * blockDim.x + threadIdx.x; i < total4; i += gridDim.x * blockDim.x) {
    f32x4 f = ((const f32x4*)K)[i];
    u16x4 o = { f2bf(f[0]), f2bf(f[1]), f2bf(f[2]), f2bf(f[3]) };
    ((u16x4*)Kb)[i] = o;
  }
}

// ---------- pre-kernel 3: V fp32 [n][s][d] -> bf16 V^T [n][d][s] ----------
__global__ void transpose_v_kernel(const float* __restrict__ V, unsigned short* __restrict__ Vt) {
  __shared__ unsigned short tile[64][72];
  const int n = blockIdx.z;
  const int s0 = blockIdx.x * 64;
  const int d0 = blockIdx.y * 64;
  const int t = threadIdx.x;
  const int tr = t >> 4;
  const int tc = (t & 15) << 2;
  const float* src = V + (((size_t)n * S_DIM) + s0) * D_DIM + d0;
#pragma unroll
  for (int rr = 0; rr < 64; rr += 16) {
    f32x4 f = *(const f32x4*)(src + (size_t)(tr + rr) * D_DIM + tc);
    tile[tr + rr][tc + 0] = f2bf(f[0]);
    tile[tr + rr][tc + 1] = f2bf(f[1]);
    tile[tr + rr][tc + 2] = f2bf(f[2]);
    tile[tr + rr][tc + 3] = f2bf(f[3]);
  }
  __syncthreads();
  unsigned short* dst = Vt + (((size_t)n * D_DIM) + d0) * (size_t)S_DIM + s0;
#pragma unroll
  for (int rr = 0; rr < 64; rr += 16) {
    const int dr = tr + rr;
    u16x4 o = { tile[tc + 0][dr], tile[tc + 1][dr], tile[tc + 2][dr], tile[tc + 3][dr] };
    *(u16x4*)(dst + (size_t)dr * S_DIM + tc) = o;
  }
}

// ---------- main fused attention: two-phase (no full-row P storage) ----------
// block: 256 threads (4 waves), one n x 16 L-rows. Wave w owns S-cols c0=s0+w*64.
// Phase 1: QK -> mask -> exp -> rsum + PV (P transposed via tiny per-wave LDS chunk).
// Phase 2: recompute QK -> exp -> scale by 1/Z -> write w (MFMA pipe is nearly idle, recompute is cheap).
__global__ __launch_bounds__(256, 4) void attn_main(
    const float* __restrict__ Q, const unsigned int* __restrict__ mbits,
    const unsigned short* __restrict__ Kb, const unsigned short* __restrict__ Vt,
    float* __restrict__ out_x, float* __restrict__ out_w) {
  __shared__ unsigned int maskw[16][64];            // 4 KB: this block's mask bits
  __shared__ unsigned short chunk[4][16][CSTRIDE];  // 10 KB: per-wave P chunk (16x64 used)
  __shared__ float xbuf[16][D_DIM];                 // 8 KB
  __shared__ float zrow[16];
  __shared__ float izrow[16];

  const int n = blockIdx.y;
  const int l0 = blockIdx.x * 16;
  const int tid = threadIdx.x;
  const int w = tid >> 6;
  const int lane = tid & 63;
  const int g = lane >> 4;
  const int lm = lane & 15;

  for (int i = tid; i < 16 * D_DIM / 4; i += 256) ((f32x4*)xbuf)[i] = (f32x4){0.f, 0.f, 0.f, 0.f};
  if (tid < 16) zrow[tid] = 0.0f;
  {
    const int4v* src = (const int4v*)(mbits + ((size_t)(n * L_DIM + l0)) * (S_DIM / 32));
    ((int4v*)maskw)[tid] = src[tid];  // 256 * 16B = 4 KB
  }
  __syncthreads();

  // Q fragments: lane holds row lm, k = ks*32 + g*8 + j
  short8 aq[4];
  {
    const float* qp = Q + (((size_t)n * L_DIM) + l0 + lm) * D_DIM + g * 8;
#pragma unroll
    for (int ks = 0; ks < 4; ++ks) {
      f32x4 f0 = *(const f32x4*)(qp + ks * 32);
      f32x4 f1 = *(const f32x4*)(qp + ks * 32 + 4);
      short8 a;
      a[0] = (short)f2bf(f0[0]); a[1] = (short)f2bf(f0[1]);
      a[2] = (short)f2bf(f0[2]); a[3] = (short)f2bf(f0[3]);
      a[4] = (short)f2bf(f1[0]); a[5] = (short)f2bf(f1[1]);
      a[6] = (short)f2bf(f1[2]); a[7] = (short)f2bf(f1[3]);
      aq[ks] = a;
    }
  }

  f32x4 accx[8];
#pragma unroll
  for (int dt = 0; dt < 8; ++dt) accx[dt] = (f32x4){0.f, 0.f, 0.f, 0.f};
  float rsum[4] = {0.f, 0.f, 0.f, 0.f};

  const float SCL = 0.08838834764831845f * 1.4426950408889634f;  // 1/sqrt(128) * log2(e)

  // ================= phase 1 =================
  for (int s0 = 0; s0 < S_DIM; s0 += 256) {
    const int c0 = s0 + w * 64;

    f32x4 accqk[4];
#pragma unroll
    for (int nt = 0; nt < 4; ++nt) {
      f32x4 acc = (f32x4){0.f, 0.f, 0.f, 0.f};
      const unsigned short* kp = Kb + (((size_t)n * S_DIM) + c0 + nt * 16 + lm) * D_DIM + g * 8;
#pragma unroll
      for (int ks = 0; ks < 4; ++ks) {
        short8 bk = *(const short8*)(kp + ks * 32);
        acc = __builtin_amdgcn_mfma_f32_16x16x32_bf16(aq[ks], bk, acc, 0, 0, 0);
      }
      accqk[nt] = acc;
    }

#pragma unroll
    for (int nt = 0; nt < 4; ++nt) {
      const int wi = ((c0 + nt * 16) >> 5);
      const int bit = ((nt & 1) << 4) + lm;
#pragma unroll
      for (int r = 0; r < 4; ++r) {
        const unsigned int mw = maskw[4 * g + r][wi];
        float p = ((mw >> bit) & 1u) ? 0.0f : exp2f(accqk[nt][r] * SCL);
        rsum[r] += p;
        chunk[w][4 * g + r][nt * 16 + lm] = f2bf(p);
      }
    }

    // same-wave LDS transpose read -> A fragments
    short8 pa[2];
#pragma unroll
    for (int kk = 0; kk < 2; ++kk)
      pa[kk] = *(const short8*)&chunk[w][lm][kk * 32 + g * 8];
#pragma unroll
    for (int dt = 0; dt < 8; ++dt) {
      const unsigned short* vp = Vt + (((size_t)n * D_DIM) + dt * 16 + lm) * (size_t)S_DIM + c0 + g * 8;
      accx[dt] = __builtin_amdgcn_mfma_f32_16x16x32_bf16(pa[0], *(const short8*)vp, accx[dt], 0, 0, 0);
      accx[dt] = __builtin_amdgcn_mfma_f32_16x16x32_bf16(pa[1], *(const short8*)(vp + 32), accx[dt], 0, 0, 0);
    }
  }

  // ---- row sums across lanes/waves ----
#pragma unroll
  for (int off = 1; off < 16; off <<= 1) {
#pragma unroll
    for (int r = 0; r < 4; ++r) rsum[r] += __shfl_xor(rsum[r], off);
  }
  if (lm == 0) {
#pragma unroll
    for (int r = 0; r < 4; ++r) atomicAdd(&zrow[4 * g + r], rsum[r]);
  }
#pragma unroll
  for (int dt = 0; dt < 8; ++dt) {
#pragma unroll
    for (int r = 0; r < 4; ++r)
      atomicAdd(&xbuf[4 * g + r][dt * 16 + lm], accx[dt][r]);
  }
  __syncthreads();
  if (tid < 16) izrow[tid] = 1.0f / zrow[tid];
  __syncthreads();

  // ---- write x (normalized) ----
  {
    float* xbase = out_x + (((size_t)n * L_DIM) + l0) * (size_t)D_DIM;
    for (int i = tid; i < 16 * (D_DIM / 4); i += 256) {
      const int r = i >> 5;
      const int c = (i & 31) << 2;
      const float iz = izrow[r];
      f32x4 o = { xbuf[r][c + 0] * iz, xbuf[r][c + 1] * iz,
                  xbuf[r][c + 2] * iz, xbuf[r][c + 3] * iz };
      __builtin_nontemporal_store(o, (f32x4*)(xbase + (size_t)r * D_DIM + c));
    }
  }

  // ================= phase 2: recompute QK, write normalized w =================
  float izr[4];
#pragma unroll
  for (int r = 0; r < 4; ++r) izr[r] = izrow[4 * g + r];
  float* wbase = out_w + (((size_t)n * L_DIM) + l0 + 4 * g) * (size_t)S_DIM;

  for (int s0 = 0; s0 < S_DIM; s0 += 256) {
    const int c0 = s0 + w * 64;

    f32x4 accqk[4];
#pragma unroll
    for (int nt = 0; nt < 4; ++nt) {
      f32x4 acc = (f32x4){0.f, 0.f, 0.f, 0.f};
      const unsigned short* kp = Kb + (((size_t)n * S_DIM) + c0 + nt * 16 + lm) * D_DIM + g * 8;
#pragma unroll
      for (int ks = 0; ks < 4; ++ks) {
        short8 bk = *(const short8*)(kp + ks * 32);
        acc = __builtin_amdgcn_mfma_f32_16x16x32_bf16(aq[ks], bk, acc, 0, 0, 0);
      }
      accqk[nt] = acc;
    }

#pragma unroll
    for (int nt = 0; nt < 4; ++nt) {
      const int col = c0 + nt * 16 + lm;
      const int wi = ((c0 + nt * 16) >> 5);
      const int bit = ((nt & 1) << 4) + lm;
#pragma unroll
      for (int r = 0; r < 4; ++r) {
        const unsigned int mw = maskw[4 * g + r][wi];
        float p = ((mw >> bit) & 1u) ? 0.0f : exp2f(accqk[nt][r] * SCL);
        __builtin_nontemporal_store(p * izr[r], wbase + (size_t)r * S_DIM + col);
      }
    }
  }
}

extern "C" void kernel_launch(void* const* d_in, const int* in_sizes, int n_in,
                              void* d_out, int out_size, void* d_ws, size_t ws_size,
                              hipStream_t stream) {
  const float* Q = (const float*)d_in[0];
  const float* K = (const float*)d_in[1];
  const float* V = (const float*)d_in[2];
  const void* mask = d_in[3];

  float* out_x = (float*)d_out;
  float* out_w = out_x + (size_t)N_B * L_DIM * D_DIM;

  unsigned short* Kb = (unsigned short*)d_ws;                        // 8 MB
  unsigned short* Vt = Kb + (size_t)N_B * S_DIM * D_DIM;             // 8 MB
  unsigned long long* bits = (unsigned long long*)(Vt + (size_t)N_B * S_DIM * D_DIM);  // 8.4 MB
  int* flag = (int*)((char*)bits + (size_t)N_B * L_DIM * S_DIM / 8);

  detect_mask_kernel<<<dim3(1), dim3(256), 0, stream>>>((const unsigned int*)mask, flag);
  pack_mask_kernel<<<dim3(4096), dim3(256), 0, stream>>>(mask, flag, bits);
  cvt_k_kernel<<<dim3(2048), dim3(256), 0, stream>>>(K, Kb);
  transpose_v_kernel<<<dim3(S_DIM / 64, D_DIM / 64, N_B), dim3(256), 0, stream>>>(V, Vt);
  attn_main<<<dim3(L_DIM / 16, N_B), dim3(256), 0, stream>>>(
      Q, (const unsigned int*)bits, Kb, Vt, out_x, out_w);
}

// Round 4
// 743.761 us; speedup vs baseline: 1.1800x; 1.1800x over previous
//
#include <hip/hip_runtime.h>
#include <hip/hip_bf16.h>

typedef float f32x4 __attribute__((ext_vector_type(4)));
typedef short short8 __attribute__((ext_vector_type(8)));
typedef unsigned short u16x4 __attribute__((ext_vector_type(4)));
typedef int int4v __attribute__((ext_vector_type(4)));

#define N_B 16
#define L_DIM 2048
#define S_DIM 2048
#define D_DIM 128
#define CSTRIDE 68   // P-chunk LDS leading dim (shorts): 34 dwords/row -> conflict-free frag writes

static __device__ __forceinline__ unsigned short f2bf(float f) {
  unsigned int u = __builtin_bit_cast(unsigned int, f);
  u = u + 0x7fffu + ((u >> 16) & 1u);
  return (unsigned short)(u >> 16);
}

// ---------- pre-kernel 0: detect mask element width ----------
__global__ void detect_mask_kernel(const unsigned int* __restrict__ m, int* __restrict__ flag) {
  __shared__ unsigned int red[256];
  unsigned int v = 0;
  for (int i = threadIdx.x; i < 16384; i += 256) v |= m[i];
  red[threadIdx.x] = v;
  __syncthreads();
  if (threadIdx.x == 0) {
    unsigned int o = 0;
#pragma unroll
    for (int i = 0; i < 256; ++i) o |= red[i];
    *flag = (o > 1u) ? 1 : 0;
  }
}

// ---------- pre-kernel 1: pack mask to bits (bit=1 -> masked) ----------
__global__ void pack_mask_kernel(const void* __restrict__ mraw, const int* __restrict__ flagp,
                                 unsigned long long* __restrict__ bits) {
  const int byte_mode = *flagp;
  const size_t total = (size_t)N_B * L_DIM * S_DIM;
  const size_t stride = (size_t)gridDim.x * blockDim.x;
  for (size_t i = (size_t)blockIdx.x * blockDim.x + threadIdx.x; i < total; i += stride) {
    int v;
    if (byte_mode) v = ((const unsigned char*)mraw)[i] != 0;
    else           v = ((const int*)mraw)[i] != 0;
    unsigned long long b = __ballot(v);
    if ((threadIdx.x & 63) == 0) bits[i >> 6] = b;
  }
}

// ---------- pre-kernel 2: K fp32 -> fragment-major bf16 ----------
// Kswz layout: [(n*128 + s16)*4 + ks] blocks of 512 shorts; lane l (g=l>>4,lm=l&15)
// holds K[n][s16*16+lm][ks*32+g*8 + 0..7] at base + l*8 shorts. Every hot-loop
// B-fragment load becomes one contiguous 1KB wave fetch.
__global__ void k_swz_kernel(const float* __restrict__ K, unsigned short* __restrict__ Kswz) {
  __shared__ float Kt[16][132];
  const int s16 = blockIdx.x;
  const int n = blockIdx.y;
  const int t = threadIdx.x;
  for (int i = t; i < 512; i += 256) {
    const int row = i >> 5;
    const int c4 = (i & 31) << 2;
    f32x4 f = *(const f32x4*)(K + (((size_t)n * S_DIM) + s16 * 16 + row) * D_DIM + c4);
    *(f32x4*)&Kt[row][c4] = f;
  }
  __syncthreads();
  const int ks = t >> 6;
  const int l = t & 63;
  const int g = l >> 4;
  const int lm = l & 15;
  short8 o;
#pragma unroll
  for (int j = 0; j < 8; ++j) o[j] = (short)f2bf(Kt[lm][ks * 32 + g * 8 + j]);
  *(short8*)(Kswz + ((size_t)n * (S_DIM * D_DIM)) + (size_t)s16 * 2048 + t * 8) = o;
}

// ---------- pre-kernel 3: V fp32 -> fragment-major bf16 (PV B-operand order) ----------
// Vswz layout: [((n*32 + sc)*2 + kk)*8 + dt] blocks of 512 shorts; lane l holds
// V[n][sc*64 + kk*32 + g*8 + j][dt*16 + lm] (= V^T fragment) at base + l*8.
__global__ void v_swz_kernel(const float* __restrict__ V, unsigned short* __restrict__ Vswz) {
  __shared__ unsigned short Vl[64][132];
  const int sc = blockIdx.x;
  const int n = blockIdx.y;
  const int t = threadIdx.x;
  for (int i = t; i < 2048; i += 256) {
    const int row = i >> 5;
    const int c4 = (i & 31) << 2;
    f32x4 f = *(const f32x4*)(V + (((size_t)n * S_DIM) + sc * 64 + row) * D_DIM + c4);
    u16x4 o = { f2bf(f[0]), f2bf(f[1]), f2bf(f[2]), f2bf(f[3]) };
    *(u16x4*)&Vl[row][c4] = o;
  }
  __syncthreads();
  for (int u = t; u < 1024; u += 256) {
    const int kk = u >> 9;
    const int dt = (u >> 6) & 7;
    const int l = u & 63;
    const int g = l >> 4;
    const int lm = l & 15;
    const int sl = kk * 32 + g * 8;
    const int d = dt * 16 + lm;
    short8 o;
#pragma unroll
    for (int j = 0; j < 8; ++j) o[j] = (short)Vl[sl + j][d];
    *(short8*)(Vswz + ((size_t)n * (S_DIM * D_DIM)) + (size_t)sc * 8192 + u * 8) = o;
  }
}

// ---------- main fused attention: two-phase, fragment-major operands ----------
__global__ __launch_bounds__(256, 4) void attn_main(
    const float* __restrict__ Q, const unsigned int* __restrict__ mbits,
    const unsigned short* __restrict__ Kswz, const unsigned short* __restrict__ Vswz,
    float* __restrict__ out_x, float* __restrict__ out_w) {
  __shared__ unsigned int maskw[16][64];            // 4 KB mask bits for this block
  __shared__ unsigned short chunk[4][16][CSTRIDE];  // per-wave P chunk (16x64 used)
  __shared__ float xbuf[16][D_DIM];
  __shared__ float zrow[16];
  __shared__ float izrow[16];

  const int n = blockIdx.y;
  const int l0 = blockIdx.x * 16;
  const int tid = threadIdx.x;
  const int w = tid >> 6;
  const int lane = tid & 63;
  const int g = lane >> 4;
  const int lm = lane & 15;

  for (int i = tid; i < 16 * D_DIM / 4; i += 256) ((f32x4*)xbuf)[i] = (f32x4){0.f, 0.f, 0.f, 0.f};
  if (tid < 16) zrow[tid] = 0.0f;
  {
    const int4v* src = (const int4v*)(mbits + ((size_t)(n * L_DIM + l0)) * (S_DIM / 32));
    ((int4v*)maskw)[tid] = src[tid];
  }
  __syncthreads();

  // Q fragments: lane holds row lm, k = ks*32 + g*8 + j
  short8 aq[4];
  {
    const float* qp = Q + (((size_t)n * L_DIM) + l0 + lm) * D_DIM + g * 8;
#pragma unroll
    for (int ks = 0; ks < 4; ++ks) {
      f32x4 f0 = *(const f32x4*)(qp + ks * 32);
      f32x4 f1 = *(const f32x4*)(qp + ks * 32 + 4);
      short8 a;
      a[0] = (short)f2bf(f0[0]); a[1] = (short)f2bf(f0[1]);
      a[2] = (short)f2bf(f0[2]); a[3] = (short)f2bf(f0[3]);
      a[4] = (short)f2bf(f1[0]); a[5] = (short)f2bf(f1[1]);
      a[6] = (short)f2bf(f1[2]); a[7] = (short)f2bf(f1[3]);
      aq[ks] = a;
    }
  }

  f32x4 accx[8];
#pragma unroll
  for (int dt = 0; dt < 8; ++dt) accx[dt] = (f32x4){0.f, 0.f, 0.f, 0.f};
  float rsum[4] = {0.f, 0.f, 0.f, 0.f};

  const float SCL = 0.08838834764831845f * 1.4426950408889634f;  // 1/sqrt(128)*log2(e)
  const unsigned short* kbase = Kswz + (size_t)n * (S_DIM * D_DIM) + lane * 8;
  const unsigned short* vbase = Vswz + (size_t)n * (S_DIM * D_DIM) + lane * 8;

  // ================= phase 1 =================
  for (int s0 = 0; s0 < S_DIM; s0 += 256) {
    const int c0 = s0 + w * 64;
    const int sc = c0 >> 6;

    f32x4 accqk[4];
#pragma unroll
    for (int nt = 0; nt < 4; ++nt) {
      f32x4 acc = (f32x4){0.f, 0.f, 0.f, 0.f};
      const unsigned short* kp = kbase + (size_t)((c0 >> 4) + nt) * 2048;
#pragma unroll
      for (int ks = 0; ks < 4; ++ks)
        acc = __builtin_amdgcn_mfma_f32_16x16x32_bf16(aq[ks], *(const short8*)(kp + ks * 512), acc, 0, 0, 0);
      accqk[nt] = acc;
    }

#pragma unroll
    for (int nt = 0; nt < 4; ++nt) {
      const int wi = ((c0 + nt * 16) >> 5);
      const int bit = ((nt & 1) << 4) + lm;
#pragma unroll
      for (int r = 0; r < 4; ++r) {
        const unsigned int mw = maskw[4 * g + r][wi];
        float p = ((mw >> bit) & 1u) ? 0.0f : exp2f(accqk[nt][r] * SCL);
        rsum[r] += p;
        chunk[w][4 * g + r][nt * 16 + lm] = f2bf(p);
      }
    }

    // same-wave LDS transpose read -> A fragments
    short8 pa[2];
#pragma unroll
    for (int kk = 0; kk < 2; ++kk)
      pa[kk] = *(const short8*)&chunk[w][lm][kk * 32 + g * 8];
    const unsigned short* v0 = vbase + (size_t)(sc * 16 + 0) * 512;
    const unsigned short* v1 = vbase + (size_t)(sc * 16 + 8) * 512;
#pragma unroll
    for (int dt = 0; dt < 8; ++dt) {
      accx[dt] = __builtin_amdgcn_mfma_f32_16x16x32_bf16(pa[0], *(const short8*)(v0 + dt * 512), accx[dt], 0, 0, 0);
      accx[dt] = __builtin_amdgcn_mfma_f32_16x16x32_bf16(pa[1], *(const short8*)(v1 + dt * 512), accx[dt], 0, 0, 0);
    }
  }

  // ---- row sums across lanes/waves ----
#pragma unroll
  for (int off = 1; off < 16; off <<= 1) {
#pragma unroll
    for (int r = 0; r < 4; ++r) rsum[r] += __shfl_xor(rsum[r], off);
  }
  if (lm == 0) {
#pragma unroll
    for (int r = 0; r < 4; ++r) atomicAdd(&zrow[4 * g + r], rsum[r]);
  }
#pragma unroll
  for (int dt = 0; dt < 8; ++dt) {
#pragma unroll
    for (int r = 0; r < 4; ++r)
      atomicAdd(&xbuf[4 * g + r][dt * 16 + lm], accx[dt][r]);
  }
  __syncthreads();
  if (tid < 16) izrow[tid] = 1.0f / zrow[tid];
  __syncthreads();

  // ---- write x (normalized) ----
  {
    float* xbase = out_x + (((size_t)n * L_DIM) + l0) * (size_t)D_DIM;
    for (int i = tid; i < 16 * (D_DIM / 4); i += 256) {
      const int r = i >> 5;
      const int c = (i & 31) << 2;
      const float iz = izrow[r];
      f32x4 o = { xbuf[r][c + 0] * iz, xbuf[r][c + 1] * iz,
                  xbuf[r][c + 2] * iz, xbuf[r][c + 3] * iz };
      __builtin_nontemporal_store(o, (f32x4*)(xbase + (size_t)r * D_DIM + c));
    }
  }

  // ================= phase 2: recompute QK, write normalized w =================
  float izr[4];
#pragma unroll
  for (int r = 0; r < 4; ++r) izr[r] = izrow[4 * g + r];
  float* wbase = out_w + (((size_t)n * L_DIM) + l0 + 4 * g) * (size_t)S_DIM;

  for (int s0 = 0; s0 < S_DIM; s0 += 256) {
    const int c0 = s0 + w * 64;

    f32x4 accqk[4];
#pragma unroll
    for (int nt = 0; nt < 4; ++nt) {
      f32x4 acc = (f32x4){0.f, 0.f, 0.f, 0.f};
      const unsigned short* kp = kbase + (size_t)((c0 >> 4) + nt) * 2048;
#pragma unroll
      for (int ks = 0; ks < 4; ++ks)
        acc = __builtin_amdgcn_mfma_f32_16x16x32_bf16(aq[ks], *(const short8*)(kp + ks * 512), acc, 0, 0, 0);
      accqk[nt] = acc;
    }

#pragma unroll
    for (int nt = 0; nt < 4; ++nt) {
      const int col = c0 + nt * 16 + lm;
      const int wi = ((c0 + nt * 16) >> 5);
      const int bit = ((nt & 1) << 4) + lm;
#pragma unroll
      for (int r = 0; r < 4; ++r) {
        const unsigned int mw = maskw[4 * g + r][wi];
        float p = ((mw >> bit) & 1u) ? 0.0f : exp2f(accqk[nt][r] * SCL);
        __builtin_nontemporal_store(p * izr[r], wbase + (size_t)r * S_DIM + col);
      }
    }
  }
}

extern "C" void kernel_launch(void* const* d_in, const int* in_sizes, int n_in,
                              void* d_out, int out_size, void* d_ws, size_t ws_size,
                              hipStream_t stream) {
  const float* Q = (const float*)d_in[0];
  const float* K = (const float*)d_in[1];
  const float* V = (const float*)d_in[2];
  const void* mask = d_in[3];

  float* out_x = (float*)d_out;
  float* out_w = out_x + (size_t)N_B * L_DIM * D_DIM;

  unsigned short* Kswz = (unsigned short*)d_ws;                       // 8 MB
  unsigned short* Vswz = Kswz + (size_t)N_B * S_DIM * D_DIM;          // 8 MB
  unsigned long long* bits = (unsigned long long*)(Vswz + (size_t)N_B * S_DIM * D_DIM);  // 8.4 MB
  int* flag = (int*)((char*)bits + (size_t)N_B * L_DIM * S_DIM / 8);

  detect_mask_kernel<<<dim3(1), dim3(256), 0, stream>>>((const unsigned int*)mask, flag);
  pack_mask_kernel<<<dim3(4096), dim3(256), 0, stream>>>(mask, flag, bits);
  k_swz_kernel<<<dim3(S_DIM / 16, N_B), dim3(256), 0, stream>>>(K, Kswz);
  v_swz_kernel<<<dim3(S_DIM / 64, N_B), dim3(256), 0, stream>>>(V, Vswz);
  attn_main<<<dim3(L_DIM / 16, N_B), dim3(256), 0, stream>>>(
      Q, (const unsigned int*)bits, Kswz, Vswz, out_x, out_w);
}